// Round 5
// baseline (2860.155 us; speedup 1.0000x reference)
//
#include <hip/hip_runtime.h>
#include <hip/hip_bf16.h>

// ---------------------------------------------------------------------------
// TTT meta-adapter fused step, round 5.
// rows = B*S = 4096, H = 1024, R = 16, V = 32000, N_valid = 4094.
// k_fused: round-4 structure + GRID-WIDE BARRIER per V-tile so all blocks of
// an XCD stay on the same 2MB lm_head window -> B-fragment loads served from
// XCD-local L2 (34.5 TB/s) instead of Infinity Cache (~8 TB/s wall observed
// in rounds 1/2/4: 16 GB / 2.05 ms each time).
// ---------------------------------------------------------------------------

#define ROWS 4096
#define Hdim 1024
#define Rdim 16
#define Vdim 32000
#define NVALID 4094.0f
#define LRATE 0.01f
#define RB 32          // rows per block in fused kernel
#define VT 512         // V-tile
#define GRIDN 256      // blocks in fused kernel (1 per CU, all co-resident)
#define NTILE 63       // ceil(32000/512); sp0: tiles 0..30, sp1: 31..62

typedef __attribute__((ext_vector_type(8))) short bf16x8;
typedef __attribute__((ext_vector_type(4))) float f32x4;

static __device__ __forceinline__ float bf2f(short u) {
  union { float f; unsigned int i; } w; w.i = ((unsigned int)(unsigned short)u) << 16; return w.f;
}
static __device__ __forceinline__ short f2bf(float f) {
  union { float f; unsigned int i; } w; w.f = f;
  unsigned int lsb = (w.i >> 16) & 1u;
  w.i += 0x7fffu + lsb;                 // round-to-nearest-even
  return (short)(w.i >> 16);
}
static __device__ __forceinline__ f32x4 mfma16(bf16x8 a, bf16x8 b, f32x4 c) {
  return __builtin_amdgcn_mfma_f32_16x16x32_bf16(a, b, c, 0, 0, 0);
}

// grid-wide barrier: monotonic arrival counter bar[0], generation bar[1].
// Safe: grid == 256 blocks, 1 block/CU on 256 CUs -> all co-resident.
static __device__ __forceinline__ void grid_barrier(unsigned* bar, int round, int tid) {
  __syncthreads();
  if (tid == 0) {
    unsigned arrived = __hip_atomic_fetch_add(&bar[0], 1u, __ATOMIC_ACQ_REL,
                                              __HIP_MEMORY_SCOPE_AGENT) + 1u;
    if (arrived == (unsigned)GRIDN * (unsigned)(round + 1)) {
      __hip_atomic_fetch_add(&bar[1], 1u, __ATOMIC_ACQ_REL, __HIP_MEMORY_SCOPE_AGENT);
    }
    while (__hip_atomic_load(&bar[1], __ATOMIC_ACQUIRE, __HIP_MEMORY_SCOPE_AGENT)
           < (unsigned)(round + 1))
      __builtin_amdgcn_s_sleep(16);
  }
  __syncthreads();
}

// ---------------- workspace layout (bytes) ----------------
#define OFF_LMH   ((size_t)0)                    // lm_head bf16 [H][V]         65,536,000
#define OFF_LMHT  ((size_t)65536000)             // lm_head^T bf16 [V][H]       65,536,000
#define OFF_ADP   ((size_t)131072000)            // adapted bf16 [ROWS][H]       8,388,608
#define OFF_DA    ((size_t)139460608)            // bf16 [ROWS][2][H] -> f32 [ROWS][H]  16,777,216
#define OFF_U     ((size_t)156237824)            // u f32                          262,144
#define OFF_DU    ((size_t)156499968)            // du f32                         262,144
#define OFF_U2    ((size_t)156762112)            // u2 f32                         262,144
#define OFF_M     ((size_t)157024256)            // m f32 [2][ROWS]                 32,768
#define OFF_Z     ((size_t)157057024)            // z f32 [2][ROWS]                 32,768
#define OFF_GA    ((size_t)157089792)            // ga f32                          65,536
#define OFF_GB    ((size_t)157155328)             // gb f32                         65,536
#define OFF_LOSS  ((size_t)157220864)            // loss accumulator                     4
#define OFF_BAR   ((size_t)157220868)            // barrier cnt+gen (2 x u32)            8

// ---------------- output layout (floats) ----------------
#define OUT_A    ((size_t)4194304)
#define OUT_B    ((size_t)4210688)
#define OUT_LOSS ((size_t)4227072)
#define OUT_GN   ((size_t)4227073)

// ===================== small fp32 kernels =====================

// fused: lm_head fp32 -> bf16 copy AND bf16 transpose
__global__ void k_prep(const float* __restrict__ in, short* __restrict__ lmh_bf,
                       short* __restrict__ lmhT) {
  __shared__ float tile[32][33];
  int v0 = blockIdx.x * 32, h0 = blockIdx.y * 32;
  int tx = threadIdx.x & 31, ty = threadIdx.x >> 5;
#pragma unroll
  for (int j = 0; j < 4; ++j) {
    float v = in[(size_t)(h0 + ty + 8 * j) * Vdim + v0 + tx];
    tile[ty + 8 * j][tx] = v;
    lmh_bf[(size_t)(h0 + ty + 8 * j) * Vdim + v0 + tx] = f2bf(v);
  }
  __syncthreads();
#pragma unroll
  for (int j = 0; j < 4; ++j)
    lmhT[(size_t)(v0 + ty + 8 * j) * Hdim + h0 + tx] = f2bf(tile[tx][ty + 8 * j]);
}

// u = hs @ a : one wave per row
__global__ void k_u(const float* __restrict__ hs, const float* __restrict__ fa,
                    float* __restrict__ u) {
  int w = threadIdx.x >> 6, lane = threadIdx.x & 63;
  int row = blockIdx.x * 4 + w;
  float acc[16];
#pragma unroll
  for (int r = 0; r < 16; ++r) acc[r] = 0.f;
  const float* hrow = hs + (size_t)row * Hdim;
  for (int h = lane; h < Hdim; h += 64) {
    float hv = hrow[h];
    const float* ar = fa + h * Rdim;
#pragma unroll
    for (int r = 0; r < 16; ++r) acc[r] += hv * ar[r];
  }
#pragma unroll
  for (int r = 0; r < 16; ++r)
    for (int off = 32; off; off >>= 1) acc[r] += __shfl_xor(acc[r], off);
  if (lane == 0) {
#pragma unroll
    for (int r = 0; r < 16; ++r) u[row * Rdim + r] = acc[r];
  }
}

// adapted = bf16(hs + u @ b)
__global__ void k_adapted(const float* __restrict__ hs, const float* __restrict__ u,
                          const float* __restrict__ fb, short* __restrict__ adp) {
  size_t gid = (size_t)blockIdx.x * 256 + threadIdx.x;
  int row = (int)(gid >> 10), h = (int)(gid & 1023);
  const float* ur = u + row * Rdim;
  float v = hs[gid];
#pragma unroll
  for (int r = 0; r < 16; ++r) v += ur[r] * fb[r * Hdim + h];
  adp[gid] = f2bf(v);
}

// ===================== fused logits + online softmax + dA partial =====================
// grid 256 (XCD-swizzled -> 128 row-groups x 2 V-splits), 1024 threads (16 waves).
__launch_bounds__(1024, 4)
__global__ void k_fused(const short* __restrict__ adp, const short* __restrict__ lmhT,
                        const short* __restrict__ lmh, short* __restrict__ dApart,
                        float* __restrict__ mpart, float* __restrict__ zpart,
                        unsigned* __restrict__ bar) {
  __shared__ __align__(16) short lA[RB * 1024];   // adapted rows, full K (swizzled)  64KB
  __shared__ __align__(16) short lP[RB * VT];     // P tile bf16 (swizzled)           32KB
  __shared__ float wred[RB * 16];
  __shared__ float zred[RB * 16];
  int tid = threadIdx.x, lane = tid & 63, w = tid >> 6;      // w in [0,16)
  int q = lane >> 4, l15 = lane & 15;
  // XCD swizzle: XCDs 0-3 get split 0, XCDs 4-7 get split 1 (2MB L2 window each)
  int L = blockIdx.x;
  int sp = (L >> 2) & 1;
  int rg = (L & 3) | ((L >> 3) << 2);
  int row0 = rg * RB;
  int tilebase = sp ? 31 : 0;          // sp0: tiles 0..30 (+1 idle), sp1: 31..62

  // stage adapted rows once
#pragma unroll
  for (int i = 0; i < 4; ++i) {
    int idx = tid + i * 1024;
    int r = idx >> 7, c8 = (idx & 127) * 8;
    bf16x8 vv = *(const bf16x8*)(adp + (size_t)(row0 + r) * Hdim + c8);
    *(bf16x8*)((char*)lA + r * 2048 + ((c8 * 2) ^ ((r & 7) << 4))) = vv;
  }

  float m_used[8], zacc[8];
  f32x4 acc[2][4];
#pragma unroll
  for (int j = 0; j < 8; ++j) { m_used[j] = -1e30f; zacc[j] = 0.f; }
#pragma unroll
  for (int rf = 0; rf < 2; ++rf)
#pragma unroll
    for (int cf = 0; cf < 4; ++cf)
#pragma unroll
      for (int i = 0; i < 4; ++i) acc[rf][cf][i] = 0.f;

  __syncthreads();

  for (int t = 0; t < 32; ++t) {
    int tile = tilebase + t;
    bool active = sp ? true : (t < 31);
    if (active) {
    int v0 = tile * VT;
    bool tail = (v0 + VT > Vdim);       // only tile 62 (256 valid cols)
    // ---------- phase 1: logits, wave w owns cols w*32..+32 ----------
    f32x4 lacc[2][2];
#pragma unroll
    for (int rf = 0; rf < 2; ++rf)
#pragma unroll
      for (int cf = 0; cf < 2; ++cf)
#pragma unroll
        for (int i = 0; i < 4; ++i) lacc[rf][cf][i] = 0.f;
#pragma unroll 8
    for (int ks = 0; ks < 32; ++ks) {
      int kgl = ks * 32 + q * 8;
      bf16x8 af[2], bfr[2];
#pragma unroll
      for (int rf = 0; rf < 2; ++rf) {
        int r = rf * 16 + l15;
        af[rf] = *(const bf16x8*)((const char*)lA + r * 2048 + ((kgl * 2) ^ ((r & 7) << 4)));
      }
#pragma unroll
      for (int cf = 0; cf < 2; ++cf) {
        int c = w * 32 + cf * 16 + l15;
        bfr[cf] = *(const bf16x8*)(lmhT + (size_t)(v0 + c) * Hdim + kgl);
      }
#pragma unroll
      for (int rf = 0; rf < 2; ++rf)
#pragma unroll
        for (int cf = 0; cf < 2; ++cf)
          lacc[rf][cf] = mfma16(af[rf], bfr[cf], lacc[rf][cf]);
    }
    // ---------- online stats (cross-wave max via LDS) ----------
#pragma unroll
    for (int rf = 0; rf < 2; ++rf)
#pragma unroll
      for (int i = 0; i < 4; ++i) {
        float v = fmaxf(lacc[rf][0][i], lacc[rf][1][i]);
#pragma unroll
        for (int off = 1; off < 16; off <<= 1) v = fmaxf(v, __shfl_xor(v, off));
        if (tail && w >= 8) v = -1e30f;
        if (l15 == 0) wred[(rf * 16 + q * 4 + i) * 16 + w] = v;
      }
    __syncthreads();
#pragma unroll
    for (int rf = 0; rf < 2; ++rf)
#pragma unroll
      for (int i = 0; i < 4; ++i) {
        int j = rf * 4 + i;
        int r = rf * 16 + q * 4 + i;
        f32x4 a = *(const f32x4*)&wred[r * 16];
        f32x4 b = *(const f32x4*)&wred[r * 16 + 4];
        f32x4 c = *(const f32x4*)&wred[r * 16 + 8];
        f32x4 d = *(const f32x4*)&wred[r * 16 + 12];
        float m01 = fmaxf(fmaxf(a[0], a[1]), fmaxf(a[2], a[3]));
        float m23 = fmaxf(fmaxf(b[0], b[1]), fmaxf(b[2], b[3]));
        float m45 = fmaxf(fmaxf(c[0], c[1]), fmaxf(c[2], c[3]));
        float m67 = fmaxf(fmaxf(d[0], d[1]), fmaxf(d[2], d[3]));
        float tmax = fmaxf(fmaxf(m01, m23), fmaxf(m45, m67));
        if (tmax > m_used[j] + 8.f) {   // deferred rescale (uniform per row)
          float f = __expf(m_used[j] - tmax);
#pragma unroll
          for (int cf = 0; cf < 4; ++cf) acc[rf][cf][i] *= f;
          zacc[j] *= f;
          m_used[j] = tmax;
        }
      }
    // ---------- phase 2: P = exp(l - m_used) -> bf16 lP ----------
#pragma unroll
    for (int rf = 0; rf < 2; ++rf)
#pragma unroll
      for (int cf = 0; cf < 2; ++cf) {
        bool cok = !tail || (w * 32 + cf * 16 < Vdim - v0);
#pragma unroll
        for (int i = 0; i < 4; ++i) {
          int j = rf * 4 + i;
          int r = rf * 16 + q * 4 + i;
          int c = w * 32 + cf * 16 + l15;
          float pv = cok ? __expf(lacc[rf][cf][i] - m_used[j]) : 0.f;
          zacc[j] += pv;
          *(short*)((char*)lP + r * (VT * 2) + ((c * 2) ^ ((r & 7) << 4))) = f2bf(pv);
        }
      }
    __syncthreads();
    // ---------- phase 3: acc += P @ lm_head^T, wave w owns h w*64..+64 ----------
#pragma unroll 4
    for (int ks = 0; ks < 16; ++ks) {
      int kb = ks * 32 + q * 8;
      bf16x8 pa[2], bg[4];
#pragma unroll
      for (int rf = 0; rf < 2; ++rf) {
        int r = rf * 16 + l15;
        pa[rf] = *(const bf16x8*)((const char*)lP + r * (VT * 2) + ((kb * 2) ^ ((r & 7) << 4)));
      }
#pragma unroll
      for (int cf = 0; cf < 4; ++cf) {
        int h = w * 64 + cf * 16 + l15;
        bg[cf] = *(const bf16x8*)(lmh + (size_t)h * Vdim + v0 + kb);
      }
#pragma unroll
      for (int rf = 0; rf < 2; ++rf)
#pragma unroll
        for (int cf = 0; cf < 4; ++cf)
          acc[rf][cf] = mfma16(pa[rf], bg[cf], acc[rf][cf]);
    }
    __syncthreads();
    }                                    // end active
    if (t < 31) grid_barrier(bar, t, tid);
  }
  // ---------- epilogue: Z reduce, write m/Z/dA-partial ----------
#pragma unroll
  for (int rf = 0; rf < 2; ++rf)
#pragma unroll
    for (int i = 0; i < 4; ++i) {
      float z = zacc[rf * 4 + i];
#pragma unroll
      for (int off = 1; off < 16; off <<= 1) z += __shfl_xor(z, off);
      if (l15 == 0) zred[(rf * 16 + q * 4 + i) * 16 + w] = z;
    }
  __syncthreads();
  if (tid < RB) {
    float z = 0.f;
#pragma unroll
    for (int k = 0; k < 16; ++k) z += zred[tid * 16 + k];
    zpart[sp * ROWS + row0 + tid] = z;
  }
  if (w == 0 && l15 == 0) {
#pragma unroll
    for (int rf = 0; rf < 2; ++rf)
#pragma unroll
      for (int i = 0; i < 4; ++i)
        mpart[sp * ROWS + row0 + rf * 16 + q * 4 + i] = m_used[rf * 4 + i];
  }
#pragma unroll
  for (int rf = 0; rf < 2; ++rf)
#pragma unroll
    for (int cf = 0; cf < 4; ++cf)
#pragma unroll
      for (int i = 0; i < 4; ++i) {
        int r = rf * 16 + q * 4 + i;
        int h = w * 64 + cf * 16 + l15;
        dApart[((size_t)(row0 + r) * 2 + sp) * Hdim + h] = f2bf(acc[rf][cf][i]);
      }
}

// ===================== merge partials + target term + loss (in place) ==============
__global__ void k_post(const short* __restrict__ adp, const float* __restrict__ lmhf,
                       const int* __restrict__ ids, const float* __restrict__ mpart,
                       const float* __restrict__ zpart, char* __restrict__ dAbytes,
                       float* __restrict__ loss_acc) {
  __shared__ float red[256];
  int row = blockIdx.x, tid = threadIdx.x;
  int b = row >> 11, s = row & 2047;
  bool valid = s < 2047;
  float m0 = mpart[row], m1 = mpart[ROWS + row];
  float z0 = zpart[row], z1 = zpart[ROWS + row];
  float m = fmaxf(m0, m1);
  float e0 = __expf(m0 - m), e1 = __expf(m1 - m);
  float Z = z0 * e0 + z1 * e1;
  float s0 = e0 / (Z * NVALID), s1 = e1 / (Z * NVALID);
  int tgt = valid ? ids[b * 2048 + s + 1] : 0;
  const short* prow = (const short*)(dAbytes + (size_t)row * 4096);
  float p0[4], p1[4], lc[4], av[4];
#pragma unroll
  for (int i = 0; i < 4; ++i) {
    int h = i * 256 + tid;
    p0[i] = bf2f(prow[h]);
    p1[i] = bf2f(prow[1024 + h]);
    lc[i] = lmhf[(size_t)h * Vdim + tgt];
    av[i] = bf2f(adp[(size_t)row * Hdim + h]);
  }
  __syncthreads();                          // all reads done before aliased writes
  float* drow = (float*)(dAbytes + (size_t)row * 4096);
  float dot = 0.f;
#pragma unroll
  for (int i = 0; i < 4; ++i) {
    int h = i * 256 + tid;
    float d = valid ? (p0[i] * s0 + p1[i] * s1 - lc[i] * (1.f / NVALID)) : 0.f;
    drow[h] = d;
    dot += av[i] * lc[i];
  }
  if (!valid) return;                       // block-uniform
  red[tid] = dot; __syncthreads();
  for (int o = 128; o; o >>= 1) {
    if (tid < o) red[tid] += red[tid + o];
    __syncthreads();
  }
  if (tid == 0) atomicAdd(loss_acc, (m + logf(Z) - red[0]) / NVALID);
}

// du = dA @ b^T : one wave per row
__global__ void k_du(const float* __restrict__ dA, const float* __restrict__ fb,
                     float* __restrict__ du) {
  int w = threadIdx.x >> 6, lane = threadIdx.x & 63;
  int row = blockIdx.x * 4 + w;
  float acc[16];
#pragma unroll
  for (int r = 0; r < 16; ++r) acc[r] = 0.f;
  const float* dr = dA + (size_t)row * Hdim;
  for (int h = lane; h < Hdim; h += 64) {
    float dv = dr[h];
#pragma unroll
    for (int r = 0; r < 16; ++r) acc[r] += dv * fb[r * Hdim + h];
  }
#pragma unroll
  for (int r = 0; r < 16; ++r)
    for (int off = 32; off; off >>= 1) acc[r] += __shfl_xor(acc[r], off);
  if (lane == 0) {
#pragma unroll
    for (int r = 0; r < 16; ++r) du[row * Rdim + r] = acc[r];
  }
}

// ga = hs^T @ du ; gb = u^T @ dA  (atomic partials over row chunks)
__global__ void k_ga_gb(const float* __restrict__ hs, const float* __restrict__ dA,
                        const float* __restrict__ u, const float* __restrict__ du,
                        float* __restrict__ ga, float* __restrict__ gb) {
  __shared__ float lu[512 * 16], ldu[512 * 16];
  int tid = threadIdx.x;
  int h = blockIdx.x * 256 + tid;
  int r0 = blockIdx.y * 512;
#pragma unroll
  for (int i = 0; i < 32; ++i) {
    int idx = tid + i * 256;
    lu[idx] = u[(size_t)r0 * Rdim + idx];
    ldu[idx] = du[(size_t)r0 * Rdim + idx];
  }
  __syncthreads();
  float aga[16], agb[16];
#pragma unroll
  for (int r = 0; r < 16; ++r) { aga[r] = 0.f; agb[r] = 0.f; }
  for (int rl = 0; rl < 512; ++rl) {
    int row = r0 + rl;
    float hv = hs[(size_t)row * Hdim + h];
    float dv = dA[(size_t)row * Hdim + h];
#pragma unroll
    for (int r = 0; r < 16; ++r) {
      aga[r] += hv * ldu[rl * 16 + r];
      agb[r] += lu[rl * 16 + r] * dv;
    }
  }
#pragma unroll
  for (int r = 0; r < 16; ++r) {
    atomicAdd(&ga[h * Rdim + r], aga[r]);
    atomicAdd(&gb[r * Hdim + h], agb[r]);
  }
}

// grad_norm + parameter update + scalars
__global__ void k_finalize(const float* __restrict__ fa, const float* __restrict__ fb,
                           const float* __restrict__ ga, const float* __restrict__ gb,
                           const float* __restrict__ loss_acc, float* __restrict__ out) {
  __shared__ float red[512];
  int tid = threadIdx.x;
  float s = 0.f;
  for (int i = tid; i < 32768; i += 512) {
    float g = ga[i];           // ga||gb contiguous in workspace
    s += g * g;
  }
  red[tid] = s; __syncthreads();
  for (int o = 256; o; o >>= 1) {
    if (tid < o) red[tid] += red[tid + o];
    __syncthreads();
  }
  float gn = sqrtf(red[0]);
  for (int i = tid; i < 16384; i += 512) {
    out[OUT_A + i] = fa[i] - LRATE * ga[i];
    out[OUT_B + i] = fb[i] - LRATE * gb[i];
  }
  if (tid == 0) { out[OUT_LOSS] = loss_acc[0]; out[OUT_GN] = gn; }
}

// u2 = hs @ new_a (new_a read from d_out)
__global__ void k_u2(const float* __restrict__ hs, const float* __restrict__ na,
                     float* __restrict__ u2) {
  int w = threadIdx.x >> 6, lane = threadIdx.x & 63;
  int row = blockIdx.x * 4 + w;
  float acc[16];
#pragma unroll
  for (int r = 0; r < 16; ++r) acc[r] = 0.f;
  const float* hrow = hs + (size_t)row * Hdim;
  for (int h = lane; h < Hdim; h += 64) {
    float hv = hrow[h];
    const float* ar = na + h * Rdim;
#pragma unroll
    for (int r = 0; r < 16; ++r) acc[r] += hv * ar[r];
  }
#pragma unroll
  for (int r = 0; r < 16; ++r)
    for (int off = 32; off; off >>= 1) acc[r] += __shfl_xor(acc[r], off);
  if (lane == 0) {
#pragma unroll
    for (int r = 0; r < 16; ++r) u2[row * Rdim + r] = acc[r];
  }
}

// out = hs + u2 @ new_b (new_b read from d_out)
__global__ void k_out(const float* __restrict__ hs, const float* __restrict__ u2,
                      const float* __restrict__ nb, float* __restrict__ out) {
  size_t gid = (size_t)blockIdx.x * 256 + threadIdx.x;
  int row = (int)(gid >> 10), h = (int)(gid & 1023);
  const float* ur = u2 + row * Rdim;
  float v = hs[gid];
#pragma unroll
  for (int r = 0; r < 16; ++r) v += ur[r] * nb[r * Hdim + h];
  out[gid] = v;
}

extern "C" void kernel_launch(void* const* d_in, const int* in_sizes, int n_in,
                              void* d_out, int out_size, void* d_ws, size_t ws_size,
                              hipStream_t stream) {
  (void)in_sizes; (void)n_in; (void)out_size; (void)ws_size;
  const float* hs   = (const float*)d_in[0];
  const int*   ids  = (const int*)d_in[1];
  const float* fa   = (const float*)d_in[2];
  const float* fb   = (const float*)d_in[3];
  const float* lmhf = (const float*)d_in[4];
  float* out = (float*)d_out;
  char* ws = (char*)d_ws;

  short* lmh_bf = (short*)(ws + OFF_LMH);
  short* lmhT   = (short*)(ws + OFF_LMHT);
  short* adp    = (short*)(ws + OFF_ADP);
  char*  dAb    = ws + OFF_DA;
  float* u      = (float*)(ws + OFF_U);
  float* du     = (float*)(ws + OFF_DU);
  float* u2     = (float*)(ws + OFF_U2);
  float* mpart  = (float*)(ws + OFF_M);
  float* zpart  = (float*)(ws + OFF_Z);
  float* ga     = (float*)(ws + OFF_GA);
  float* gb     = (float*)(ws + OFF_GB);
  float* loss_acc = (float*)(ws + OFF_LOSS);
  unsigned* bar = (unsigned*)(ws + OFF_BAR);

  hipMemsetAsync(ws + OFF_GA, 0, 65536 * 2 + 12, stream);  // ga, gb, loss, barrier

  k_prep<<<dim3(1000, 32), 256, 0, stream>>>(lmhf, lmh_bf, lmhT);
  k_u<<<1024, 256, 0, stream>>>(hs, fa, u);
  k_adapted<<<16384, 256, 0, stream>>>(hs, u, fb, adp);
  k_fused<<<256, 1024, 0, stream>>>(adp, lmhT, lmh_bf, (short*)dAb, mpart, zpart, bar);
  k_post<<<4096, 256, 0, stream>>>(adp, lmhf, ids, mpart, zpart, dAb, loss_acc);
  k_du<<<1024, 256, 0, stream>>>((float*)dAb, fb, du);
  k_ga_gb<<<dim3(4, 8), 256, 0, stream>>>(hs, (float*)dAb, u, du, ga, gb);
  k_finalize<<<1, 512, 0, stream>>>(fa, fb, ga, gb, loss_acc, out);
  k_u2<<<1024, 256, 0, stream>>>(hs, out + OUT_A, u2);
  k_out<<<16384, 256, 0, stream>>>(hs, u2, out + OUT_B, out);
}

// Round 6
// 1520.304 us; speedup vs baseline: 1.8813x; 1.8813x over previous
//
#include <hip/hip_runtime.h>
#include <hip/hip_bf16.h>

// ---------------------------------------------------------------------------
// TTT meta-adapter fused step, round 6.
// rows = B*S = 4096, H = 1024, R = 16, V = 32000, N_valid = 4094.
// k_fused (R4 structure) but lm_head is PRE-PACKED into MFMA-fragment order
// (k_pack) so every global B-fragment load is one contiguous 1KB wave load
// instead of a 16-way scattered gather (the R1-R5 ~64cyc/load wall).
// ---------------------------------------------------------------------------

#define ROWS 4096
#define Hdim 1024
#define Rdim 16
#define Vdim 32000
#define NVALID 4094.0f
#define LRATE 0.01f
#define RB 32          // rows per block in fused kernel
#define VT 512         // V-tile

typedef __attribute__((ext_vector_type(8))) short bf16x8;
typedef __attribute__((ext_vector_type(4))) float f32x4;

static __device__ __forceinline__ float bf2f(short u) {
  union { float f; unsigned int i; } w; w.i = ((unsigned int)(unsigned short)u) << 16; return w.f;
}
static __device__ __forceinline__ short f2bf(float f) {
  union { float f; unsigned int i; } w; w.f = f;
  unsigned int lsb = (w.i >> 16) & 1u;
  w.i += 0x7fffu + lsb;                 // round-to-nearest-even
  return (short)(w.i >> 16);
}
static __device__ __forceinline__ f32x4 mfma16(bf16x8 a, bf16x8 b, f32x4 c) {
  return __builtin_amdgcn_mfma_f32_16x16x32_bf16(a, b, c, 0, 0, 0);
}

// ---------------- workspace layout (bytes) ----------------
#define OFF_BP2   ((size_t)0)                    // lm_head packed [64][1000][512] bf16  65,536,000
#define OFF_BP1   ((size_t)65536000)             // lmhT packed [2000][32][512] bf16     65,536,000
#define OFF_ADP   ((size_t)131072000)            // adapted bf16 [ROWS][H]       8,388,608
#define OFF_DA    ((size_t)139460608)            // bf16 [ROWS][2][H] -> f32 [ROWS][H]  16,777,216
#define OFF_U     ((size_t)156237824)            // u f32                          262,144
#define OFF_DU    ((size_t)156499968)            // du f32                         262,144
#define OFF_U2    ((size_t)156762112)            // u2 f32                         262,144
#define OFF_M     ((size_t)157024256)            // m f32 [2][ROWS]                 32,768
#define OFF_Z     ((size_t)157057024)            // z f32 [2][ROWS]                 32,768
#define OFF_GA    ((size_t)157089792)            // ga f32                          65,536
#define OFF_GB    ((size_t)157155328)            // gb f32                          65,536
#define OFF_LOSS  ((size_t)157220864)            // loss accumulator                     4

// ---------------- output layout (floats) ----------------
#define OUT_A    ((size_t)4194304)
#define OUT_B    ((size_t)4210688)
#define OUT_LOSS ((size_t)4227072)
#define OUT_GN   ((size_t)4227073)

// ===================== pack lm_head into fragment order =====================
// Bp1[vb][kb][lane][8]: element (v,k)=lm_head[k][v], lane=(v&15)+16*((k>>3)&3), j=k&7
// Bp2[hb][vkb][lane][8]: element (h,v)=lm_head[h][v], lane=(h&15)+16*((v>>3)&3), j=v&7
__global__ void k_pack(const float* __restrict__ in, short* __restrict__ Bp1,
                       short* __restrict__ Bp2) {
  __shared__ short tile[32][258];
  int v0 = blockIdx.x * 256, k0 = blockIdx.y * 32;
  int tid = threadIdx.x;
#pragma unroll
  for (int r = 0; r < 32; ++r)
    tile[r][tid] = f2bf(in[(size_t)(k0 + r) * Vdim + v0 + tid]);
  __syncthreads();
  int lane = tid & 63, l15 = lane & 15, q = (lane >> 4) & 3, g = tid >> 6;
#pragma unroll
  for (int it = 0; it < 4; ++it) {
    int vbl = it * 4 + g;                 // 0..15
    bf16x8 frag;
#pragma unroll
    for (int j = 0; j < 8; ++j) frag[j] = tile[q * 8 + j][vbl * 16 + l15];
    *(bf16x8*)(Bp1 + ((size_t)(v0 / 16 + vbl) * 32 + k0 / 32) * 512 + lane * 8) = frag;
  }
#pragma unroll
  for (int it = 0; it < 4; ++it) {
    int idx = it * 4 + g;                 // 0..15: hbl=idx>>3 (0..1), vkbl=idx&7
    int hbl = idx >> 3, vkbl = idx & 7;
    bf16x8 frag;
#pragma unroll
    for (int j = 0; j < 8; ++j) frag[j] = tile[hbl * 16 + l15][vkbl * 32 + q * 8 + j];
    *(bf16x8*)(Bp2 + ((size_t)(k0 / 16 + hbl) * 1000 + v0 / 32 + vkbl) * 512 + lane * 8) = frag;
  }
}

// ===================== small fp32 kernels =====================

// u = hs @ a : one wave per row
__global__ void k_u(const float* __restrict__ hs, const float* __restrict__ fa,
                    float* __restrict__ u) {
  int w = threadIdx.x >> 6, lane = threadIdx.x & 63;
  int row = blockIdx.x * 4 + w;
  float acc[16];
#pragma unroll
  for (int r = 0; r < 16; ++r) acc[r] = 0.f;
  const float* hrow = hs + (size_t)row * Hdim;
  for (int h = lane; h < Hdim; h += 64) {
    float hv = hrow[h];
    const float* ar = fa + h * Rdim;
#pragma unroll
    for (int r = 0; r < 16; ++r) acc[r] += hv * ar[r];
  }
#pragma unroll
  for (int r = 0; r < 16; ++r)
    for (int off = 32; off; off >>= 1) acc[r] += __shfl_xor(acc[r], off);
  if (lane == 0) {
#pragma unroll
    for (int r = 0; r < 16; ++r) u[row * Rdim + r] = acc[r];
  }
}

// adapted = bf16(hs + u @ b)
__global__ void k_adapted(const float* __restrict__ hs, const float* __restrict__ u,
                          const float* __restrict__ fb, short* __restrict__ adp) {
  size_t gid = (size_t)blockIdx.x * 256 + threadIdx.x;
  int row = (int)(gid >> 10), h = (int)(gid & 1023);
  const float* ur = u + row * Rdim;
  float v = hs[gid];
#pragma unroll
  for (int r = 0; r < 16; ++r) v += ur[r] * fb[r * Hdim + h];
  adp[gid] = f2bf(v);
}

// ===================== fused logits + online softmax + dA partial =====================
// grid 256 (XCD-swizzled -> 128 row-groups x 2 V-splits), 1024 threads (16 waves).
__launch_bounds__(1024, 4)
__global__ void k_fused(const short* __restrict__ adp, const short* __restrict__ Bp1,
                        const short* __restrict__ Bp2, short* __restrict__ dApart,
                        float* __restrict__ mpart, float* __restrict__ zpart) {
  __shared__ __align__(16) short lA[RB * 1024];   // adapted rows, full K (swizzled)  64KB
  __shared__ __align__(16) short lP[RB * VT];     // P tile bf16 (swizzled)           32KB
  __shared__ float wred[RB * 16];
  __shared__ float zred[RB * 16];
  int tid = threadIdx.x, lane = tid & 63, w = tid >> 6;      // w in [0,16)
  int q = lane >> 4, l15 = lane & 15;
  // XCD swizzle: XCDs 0-3 get split 0, XCDs 4-7 get split 1
  int L = blockIdx.x;
  int sp = (L >> 2) & 1;
  int rg = (L & 3) | ((L >> 3) << 2);
  int row0 = rg * RB;
  int v0beg = sp ? 15872 : 0;
  int v0end = sp ? 32000 : 15872;

  // stage adapted rows once
#pragma unroll
  for (int i = 0; i < 4; ++i) {
    int idx = tid + i * 1024;
    int r = idx >> 7, c8 = (idx & 127) * 8;
    bf16x8 vv = *(const bf16x8*)(adp + (size_t)(row0 + r) * Hdim + c8);
    *(bf16x8*)((char*)lA + r * 2048 + ((c8 * 2) ^ ((r & 7) << 4))) = vv;
  }

  float m_used[8], zacc[8];
  f32x4 acc[2][4];
#pragma unroll
  for (int j = 0; j < 8; ++j) { m_used[j] = -1e30f; zacc[j] = 0.f; }
#pragma unroll
  for (int rf = 0; rf < 2; ++rf)
#pragma unroll
    for (int cf = 0; cf < 4; ++cf)
#pragma unroll
      for (int i = 0; i < 4; ++i) acc[rf][cf][i] = 0.f;

  __syncthreads();

  for (int v0 = v0beg; v0 < v0end; v0 += VT) {
    bool tail = (v0 + VT > Vdim);       // only last tile of sp=1 (256 valid cols)
    // ---------- phase 1: logits, wave w owns cols w*32..+32 ----------
    f32x4 lacc[2][2];
#pragma unroll
    for (int rf = 0; rf < 2; ++rf)
#pragma unroll
      for (int cf = 0; cf < 2; ++cf)
#pragma unroll
        for (int i = 0; i < 4; ++i) lacc[rf][cf][i] = 0.f;
    int vbase = v0 / 16 + w * 2;        // Bp1 vb base for this wave
#pragma unroll 8
    for (int ks = 0; ks < 32; ++ks) {
      int kgl = ks * 32 + q * 8;
      bf16x8 af[2], bfr[2];
#pragma unroll
      for (int rf = 0; rf < 2; ++rf) {
        int r = rf * 16 + l15;
        af[rf] = *(const bf16x8*)((const char*)lA + r * 2048 + ((kgl * 2) ^ ((r & 7) << 4)));
      }
#pragma unroll
      for (int cf = 0; cf < 2; ++cf)
        bfr[cf] = *(const bf16x8*)(Bp1 + ((size_t)(vbase + cf) * 32 + ks) * 512 + lane * 8);
#pragma unroll
      for (int rf = 0; rf < 2; ++rf)
#pragma unroll
        for (int cf = 0; cf < 2; ++cf)
          lacc[rf][cf] = mfma16(af[rf], bfr[cf], lacc[rf][cf]);
    }
    // ---------- online stats (cross-wave max via LDS) ----------
#pragma unroll
    for (int rf = 0; rf < 2; ++rf)
#pragma unroll
      for (int i = 0; i < 4; ++i) {
        float v = fmaxf(lacc[rf][0][i], lacc[rf][1][i]);
#pragma unroll
        for (int off = 1; off < 16; off <<= 1) v = fmaxf(v, __shfl_xor(v, off));
        if (tail && w >= 8) v = -1e30f;
        if (l15 == 0) wred[(rf * 16 + q * 4 + i) * 16 + w] = v;
      }
    __syncthreads();
#pragma unroll
    for (int rf = 0; rf < 2; ++rf)
#pragma unroll
      for (int i = 0; i < 4; ++i) {
        int j = rf * 4 + i;
        int r = rf * 16 + q * 4 + i;
        f32x4 a = *(const f32x4*)&wred[r * 16];
        f32x4 b = *(const f32x4*)&wred[r * 16 + 4];
        f32x4 c = *(const f32x4*)&wred[r * 16 + 8];
        f32x4 d = *(const f32x4*)&wred[r * 16 + 12];
        float m01 = fmaxf(fmaxf(a[0], a[1]), fmaxf(a[2], a[3]));
        float m23 = fmaxf(fmaxf(b[0], b[1]), fmaxf(b[2], b[3]));
        float m45 = fmaxf(fmaxf(c[0], c[1]), fmaxf(c[2], c[3]));
        float m67 = fmaxf(fmaxf(d[0], d[1]), fmaxf(d[2], d[3]));
        float tmax = fmaxf(fmaxf(m01, m23), fmaxf(m45, m67));
        if (tmax > m_used[j] + 8.f) {   // deferred rescale (uniform per row)
          float f = __expf(m_used[j] - tmax);
#pragma unroll
          for (int cf = 0; cf < 4; ++cf) acc[rf][cf][i] *= f;
          zacc[j] *= f;
          m_used[j] = tmax;
        }
      }
    // ---------- phase 2: P = exp(l - m_used) -> bf16 lP ----------
#pragma unroll
    for (int rf = 0; rf < 2; ++rf)
#pragma unroll
      for (int cf = 0; cf < 2; ++cf) {
        bool cok = !tail || (w * 32 + cf * 16 < Vdim - v0);
#pragma unroll
        for (int i = 0; i < 4; ++i) {
          int j = rf * 4 + i;
          int r = rf * 16 + q * 4 + i;
          int c = w * 32 + cf * 16 + l15;
          float pv = cok ? __expf(lacc[rf][cf][i] - m_used[j]) : 0.f;
          zacc[j] += pv;
          *(short*)((char*)lP + r * (VT * 2) + ((c * 2) ^ ((r & 7) << 4))) = f2bf(pv);
        }
      }
    __syncthreads();
    // ---------- phase 3: acc += P @ lm_head^T, wave w owns h w*64..+64 ----------
    int vk0 = v0 / 32;                  // Bp2 vkb base for this tile
#pragma unroll 4
    for (int ks = 0; ks < 16; ++ks) {
      int kb = ks * 32 + q * 8;
      bf16x8 pa[2], bg[4];
#pragma unroll
      for (int rf = 0; rf < 2; ++rf) {
        int r = rf * 16 + l15;
        pa[rf] = *(const bf16x8*)((const char*)lP + r * (VT * 2) + ((kb * 2) ^ ((r & 7) << 4)));
      }
#pragma unroll
      for (int cf = 0; cf < 4; ++cf)
        bg[cf] = *(const bf16x8*)(Bp2 + ((size_t)(w * 4 + cf) * 1000 + vk0 + ks) * 512 + lane * 8);
#pragma unroll
      for (int rf = 0; rf < 2; ++rf)
#pragma unroll
        for (int cf = 0; cf < 4; ++cf)
          acc[rf][cf] = mfma16(pa[rf], bg[cf], acc[rf][cf]);
    }
    __syncthreads();
  }
  // ---------- epilogue: Z reduce, write m/Z/dA-partial ----------
#pragma unroll
  for (int rf = 0; rf < 2; ++rf)
#pragma unroll
    for (int i = 0; i < 4; ++i) {
      float z = zacc[rf * 4 + i];
#pragma unroll
      for (int off = 1; off < 16; off <<= 1) z += __shfl_xor(z, off);
      if (l15 == 0) zred[(rf * 16 + q * 4 + i) * 16 + w] = z;
    }
  __syncthreads();
  if (tid < RB) {
    float z = 0.f;
#pragma unroll
    for (int k = 0; k < 16; ++k) z += zred[tid * 16 + k];
    zpart[sp * ROWS + row0 + tid] = z;
  }
  if (w == 0 && l15 == 0) {
#pragma unroll
    for (int rf = 0; rf < 2; ++rf)
#pragma unroll
      for (int i = 0; i < 4; ++i)
        mpart[sp * ROWS + row0 + rf * 16 + q * 4 + i] = m_used[rf * 4 + i];
  }
#pragma unroll
  for (int rf = 0; rf < 2; ++rf)
#pragma unroll
    for (int cf = 0; cf < 4; ++cf)
#pragma unroll
      for (int i = 0; i < 4; ++i) {
        int r = rf * 16 + q * 4 + i;
        int h = w * 64 + cf * 16 + l15;
        dApart[((size_t)(row0 + r) * 2 + sp) * Hdim + h] = f2bf(acc[rf][cf][i]);
      }
}

// ===================== merge partials + target term + loss (in place) ==============
__global__ void k_post(const short* __restrict__ adp, const float* __restrict__ lmhf,
                       const int* __restrict__ ids, const float* __restrict__ mpart,
                       const float* __restrict__ zpart, char* __restrict__ dAbytes,
                       float* __restrict__ loss_acc) {
  __shared__ float red[256];
  int row = blockIdx.x, tid = threadIdx.x;
  int b = row >> 11, s = row & 2047;
  bool valid = s < 2047;
  float m0 = mpart[row], m1 = mpart[ROWS + row];
  float z0 = zpart[row], z1 = zpart[ROWS + row];
  float m = fmaxf(m0, m1);
  float e0 = __expf(m0 - m), e1 = __expf(m1 - m);
  float Z = z0 * e0 + z1 * e1;
  float s0 = e0 / (Z * NVALID), s1 = e1 / (Z * NVALID);
  int tgt = valid ? ids[b * 2048 + s + 1] : 0;
  const short* prow = (const short*)(dAbytes + (size_t)row * 4096);
  float p0[4], p1[4], lc[4], av[4];
#pragma unroll
  for (int i = 0; i < 4; ++i) {
    int h = i * 256 + tid;
    p0[i] = bf2f(prow[h]);
    p1[i] = bf2f(prow[1024 + h]);
    lc[i] = lmhf[(size_t)h * Vdim + tgt];
    av[i] = bf2f(adp[(size_t)row * Hdim + h]);
  }
  __syncthreads();                          // all reads done before aliased writes
  float* drow = (float*)(dAbytes + (size_t)row * 4096);
  float dot = 0.f;
#pragma unroll
  for (int i = 0; i < 4; ++i) {
    int h = i * 256 + tid;
    float d = valid ? (p0[i] * s0 + p1[i] * s1 - lc[i] * (1.f / NVALID)) : 0.f;
    drow[h] = d;
    dot += av[i] * lc[i];
  }
  if (!valid) return;                       // block-uniform
  red[tid] = dot; __syncthreads();
  for (int o = 128; o; o >>= 1) {
    if (tid < o) red[tid] += red[tid + o];
    __syncthreads();
  }
  if (tid == 0) atomicAdd(loss_acc, (m + logf(Z) - red[0]) / NVALID);
}

// du = dA @ b^T : one wave per row
__global__ void k_du(const float* __restrict__ dA, const float* __restrict__ fb,
                     float* __restrict__ du) {
  int w = threadIdx.x >> 6, lane = threadIdx.x & 63;
  int row = blockIdx.x * 4 + w;
  float acc[16];
#pragma unroll
  for (int r = 0; r < 16; ++r) acc[r] = 0.f;
  const float* dr = dA + (size_t)row * Hdim;
  for (int h = lane; h < Hdim; h += 64) {
    float dv = dr[h];
#pragma unroll
    for (int r = 0; r < 16; ++r) acc[r] += dv * fb[r * Hdim + h];
  }
#pragma unroll
  for (int r = 0; r < 16; ++r)
    for (int off = 32; off; off >>= 1) acc[r] += __shfl_xor(acc[r], off);
  if (lane == 0) {
#pragma unroll
    for (int r = 0; r < 16; ++r) du[row * Rdim + r] = acc[r];
  }
}

// ga = hs^T @ du ; gb = u^T @ dA  (atomic partials over row chunks)
__global__ void k_ga_gb(const float* __restrict__ hs, const float* __restrict__ dA,
                        const float* __restrict__ u, const float* __restrict__ du,
                        float* __restrict__ ga, float* __restrict__ gb) {
  __shared__ float lu[512 * 16], ldu[512 * 16];
  int tid = threadIdx.x;
  int h = blockIdx.x * 256 + tid;
  int r0 = blockIdx.y * 512;
#pragma unroll
  for (int i = 0; i < 32; ++i) {
    int idx = tid + i * 256;
    lu[idx] = u[(size_t)r0 * Rdim + idx];
    ldu[idx] = du[(size_t)r0 * Rdim + idx];
  }
  __syncthreads();
  float aga[16], agb[16];
#pragma unroll
  for (int r = 0; r < 16; ++r) { aga[r] = 0.f; agb[r] = 0.f; }
  for (int rl = 0; rl < 512; ++rl) {
    int row = r0 + rl;
    float hv = hs[(size_t)row * Hdim + h];
    float dv = dA[(size_t)row * Hdim + h];
#pragma unroll
    for (int r = 0; r < 16; ++r) {
      aga[r] += hv * ldu[rl * 16 + r];
      agb[r] += lu[rl * 16 + r] * dv;
    }
  }
#pragma unroll
  for (int r = 0; r < 16; ++r) {
    atomicAdd(&ga[h * Rdim + r], aga[r]);
    atomicAdd(&gb[r * Hdim + h], agb[r]);
  }
}

// grad_norm + parameter update + scalars
__global__ void k_finalize(const float* __restrict__ fa, const float* __restrict__ fb,
                           const float* __restrict__ ga, const float* __restrict__ gb,
                           const float* __restrict__ loss_acc, float* __restrict__ out) {
  __shared__ float red[512];
  int tid = threadIdx.x;
  float s = 0.f;
  for (int i = tid; i < 32768; i += 512) {
    float g = ga[i];           // ga||gb contiguous in workspace
    s += g * g;
  }
  red[tid] = s; __syncthreads();
  for (int o = 256; o; o >>= 1) {
    if (tid < o) red[tid] += red[tid + o];
    __syncthreads();
  }
  float gn = sqrtf(red[0]);
  for (int i = tid; i < 16384; i += 512) {
    out[OUT_A + i] = fa[i] - LRATE * ga[i];
    out[OUT_B + i] = fb[i] - LRATE * gb[i];
  }
  if (tid == 0) { out[OUT_LOSS] = loss_acc[0]; out[OUT_GN] = gn; }
}

// u2 = hs @ new_a (new_a read from d_out)
__global__ void k_u2(const float* __restrict__ hs, const float* __restrict__ na,
                     float* __restrict__ u2) {
  int w = threadIdx.x >> 6, lane = threadIdx.x & 63;
  int row = blockIdx.x * 4 + w;
  float acc[16];
#pragma unroll
  for (int r = 0; r < 16; ++r) acc[r] = 0.f;
  const float* hrow = hs + (size_t)row * Hdim;
  for (int h = lane; h < Hdim; h += 64) {
    float hv = hrow[h];
    const float* ar = na + h * Rdim;
#pragma unroll
    for (int r = 0; r < 16; ++r) acc[r] += hv * ar[r];
  }
#pragma unroll
  for (int r = 0; r < 16; ++r)
    for (int off = 32; off; off >>= 1) acc[r] += __shfl_xor(acc[r], off);
  if (lane == 0) {
#pragma unroll
    for (int r = 0; r < 16; ++r) u2[row * Rdim + r] = acc[r];
  }
}

// out = hs + u2 @ new_b (new_b read from d_out)
__global__ void k_out(const float* __restrict__ hs, const float* __restrict__ u2,
                      const float* __restrict__ nb, float* __restrict__ out) {
  size_t gid = (size_t)blockIdx.x * 256 + threadIdx.x;
  int row = (int)(gid >> 10), h = (int)(gid & 1023);
  const float* ur = u2 + row * Rdim;
  float v = hs[gid];
#pragma unroll
  for (int r = 0; r < 16; ++r) v += ur[r] * nb[r * Hdim + h];
  out[gid] = v;
}

extern "C" void kernel_launch(void* const* d_in, const int* in_sizes, int n_in,
                              void* d_out, int out_size, void* d_ws, size_t ws_size,
                              hipStream_t stream) {
  (void)in_sizes; (void)n_in; (void)out_size; (void)ws_size;
  const float* hs   = (const float*)d_in[0];
  const int*   ids  = (const int*)d_in[1];
  const float* fa   = (const float*)d_in[2];
  const float* fb   = (const float*)d_in[3];
  const float* lmhf = (const float*)d_in[4];
  float* out = (float*)d_out;
  char* ws = (char*)d_ws;

  short* Bp2    = (short*)(ws + OFF_BP2);
  short* Bp1    = (short*)(ws + OFF_BP1);
  short* adp    = (short*)(ws + OFF_ADP);
  char*  dAb    = ws + OFF_DA;
  float* u      = (float*)(ws + OFF_U);
  float* du     = (float*)(ws + OFF_DU);
  float* u2     = (float*)(ws + OFF_U2);
  float* mpart  = (float*)(ws + OFF_M);
  float* zpart  = (float*)(ws + OFF_Z);
  float* ga     = (float*)(ws + OFF_GA);
  float* gb     = (float*)(ws + OFF_GB);
  float* loss_acc = (float*)(ws + OFF_LOSS);

  hipMemsetAsync(ws + OFF_GA, 0, 65536 * 2 + 4, stream);   // ga, gb, loss

  k_pack<<<dim3(125, 32), 256, 0, stream>>>(lmhf, Bp1, Bp2);
  k_u<<<1024, 256, 0, stream>>>(hs, fa, u);
  k_adapted<<<16384, 256, 0, stream>>>(hs, u, fb, adp);
  k_fused<<<256, 1024, 0, stream>>>(adp, Bp1, Bp2, (short*)dAb, mpart, zpart);
  k_post<<<4096, 256, 0, stream>>>(adp, lmhf, ids, mpart, zpart, dAb, loss_acc);
  k_du<<<1024, 256, 0, stream>>>((float*)dAb, fb, du);
  k_ga_gb<<<dim3(4, 8), 256, 0, stream>>>(hs, (float*)dAb, u, du, ga, gb);
  k_finalize<<<1, 512, 0, stream>>>(fa, fb, ga, gb, loss_acc, out);
  k_u2<<<1024, 256, 0, stream>>>(hs, out + OUT_A, u2);
  k_out<<<16384, 256, 0, stream>>>(hs, u2, out + OUT_B, out);
}